// Round 2
// baseline (461.858 us; speedup 1.0000x reference)
//
#include <hip/hip_runtime.h>
#include <cstdint>
#include <cstddef>

#define H 1024
#define BB 8
#define SS 2048
#define MROWS (BB*SS)   // 16384

typedef float  f32x4 __attribute__((ext_vector_type(4)));
typedef short  s16x8 __attribute__((ext_vector_type(8)));
typedef unsigned short u16x4 __attribute__((ext_vector_type(4)));
typedef unsigned short u16x8 __attribute__((ext_vector_type(8)));

__device__ __forceinline__ float b2f(unsigned short u) {
  union { unsigned int i; float f; } x; x.i = ((unsigned int)u) << 16; return x.f;
}
__device__ __forceinline__ unsigned short f2b(float f) {
  union { float f; unsigned int i; } x; x.f = f;
  unsigned int r = x.i + 0x7FFFu + ((x.i >> 16) & 1u);
  return (unsigned short)(r >> 16);
}

// NOTE: non-const AS(1) type — builtin prototype is "vv*1v*3IUiIiIUi" (no const);
// C-style cast strips const from the incoming pointer legally.
typedef __attribute__((address_space(1))) unsigned int guint;
typedef __attribute__((address_space(3))) unsigned int luint;
__device__ __forceinline__ void gld_lds16(const void* g, void* l) {
  __builtin_amdgcn_global_load_lds((guint*)g, (luint*)l, 16, 0, 0);
}

// ---------------- norms + scale + cast to bf16 ----------------
__global__ void norms_cast(const float* __restrict__ X, unsigned short* __restrict__ Xs,
                           float* __restrict__ norms) {
  const int row  = blockIdx.x * 4 + (threadIdx.x >> 6);
  const int lane = threadIdx.x & 63;
  const float4* xr = (const float4*)(X + (size_t)row * H);
  float4 d[4]; float s = 0.f;
#pragma unroll
  for (int j = 0; j < 4; ++j) {
    d[j] = xr[lane + j * 64];
    s += d[j].x*d[j].x + d[j].y*d[j].y + d[j].z*d[j].z + d[j].w*d[j].w;
  }
#pragma unroll
  for (int o = 32; o; o >>= 1) s += __shfl_xor(s, o);
  const float nrm = sqrtf(s);
  const float inv = 1.f / (nrm + 1e-9f);
  if (lane == 0) norms[row] = nrm;
  unsigned short* xo = Xs + (size_t)row * H;
#pragma unroll
  for (int j = 0; j < 4; ++j) {
    u16x4 o4;
    o4[0] = f2b(d[j].x * inv); o4[1] = f2b(d[j].y * inv);
    o4[2] = f2b(d[j].z * inv); o4[3] = f2b(d[j].w * inv);
    *(u16x4*)(xo + (size_t)(lane + j * 64) * 4) = o4;
  }
}

// ---------------- elementwise cast ----------------
__global__ void cast_f32_bf16(const float* __restrict__ in, unsigned short* __restrict__ out) {
  const size_t i = ((size_t)blockIdx.x * 256 + threadIdx.x) * 4;
  float4 d = *(const float4*)(in + i);
  u16x4 o; o[0] = f2b(d.x); o[1] = f2b(d.y); o[2] = f2b(d.z); o[3] = f2b(d.w);
  *(u16x4*)(out + i) = o;
}

// ---------------- transpose fp32 -> bf16 (anomaly matrix) ----------------
__global__ void transpose_cast_f32(const float* __restrict__ in, unsigned short* __restrict__ out) {
  __shared__ float t[32][33];
  const int c0 = blockIdx.x * 32, r0 = blockIdx.y * 32;
  const int tx = threadIdx.x, ty = threadIdx.y;
#pragma unroll
  for (int j = 0; j < 4; ++j)
    t[ty + j * 8][tx] = in[(size_t)(r0 + ty + j * 8) * H + c0 + tx];
  __syncthreads();
#pragma unroll
  for (int j = 0; j < 4; ++j)
    out[(size_t)(c0 + ty + j * 8) * H + r0 + tx] = f2b(t[tx][ty + j * 8]);
}

// ---------------- batched bf16 transpose (v -> vT per batch) ----------------
__global__ void transpose_bf16(const unsigned short* __restrict__ in, unsigned short* __restrict__ out) {
  __shared__ unsigned short t[32][33];
  const size_t zo = (size_t)blockIdx.z * SS * H;
  const int c0 = blockIdx.x * 32, r0 = blockIdx.y * 32;
  const int tx = threadIdx.x, ty = threadIdx.y;
#pragma unroll
  for (int j = 0; j < 4; ++j)
    t[ty + j * 8][tx] = in[zo + (size_t)(r0 + ty + j * 8) * H + c0 + tx];
  __syncthreads();
#pragma unroll
  for (int j = 0; j < 4; ++j)
    out[zo + (size_t)(c0 + ty + j * 8) * SS + r0 + tx] = t[tx][ty + j * 8];
}

// ---------------- NT GEMM: C[m,n] = sum_k A[m,k]*B[n,k], bf16 in, fp32 acc ----------------
// 128x128 tile, BK=64, 256 threads (4 waves, 2x2 of 64x64), global_load_lds + XOR swizzle.
// Staging (rule 21): LDS linear dest base+lane*16; global source column-slot pre-swizzled
// by (l&7)^(row&7); reads apply the same XOR involution -> 2-way conflict max (free, m136).
// EPI: 0 = bf16 out + bias[col]; 1 = bf16 out; 2 = bf16 out * (1/32); 3 = f32 out * norms[row]*rs[row]
template <int EPI>
__global__ __launch_bounds__(256, 2)
void gemm_nt(const unsigned short* __restrict__ A, int lda,
             const unsigned short* __restrict__ B0, int ldb, long sB,
             void* __restrict__ Cv, int ldc,
             const float* __restrict__ bias,
             const float* __restrict__ norms, const float* __restrict__ rs,
             int K) {
  __shared__ unsigned short Asm[128 * 64];
  __shared__ unsigned short Bsm[128 * 64];
  const int tid  = threadIdx.x;
  const int lane = tid & 63;
  const int w    = tid >> 6;
  const int bm = blockIdx.y, bn = blockIdx.x;
  const int b  = bm >> 4;  // 16 M-tiles per batch (2048 rows)
  const unsigned short* Ap = A  + (size_t)bm * 128 * lda;
  const unsigned short* Bp = B0 + (size_t)b * sB + (size_t)bn * 128 * ldb;

  // staging: call c covers rows [c*32, c*32+32); lane writes LDS (row, slot l&7),
  // sourcing global column-slot (l&7)^(row&7) (inverse swizzle)
  const int st_row = w * 8 + (lane >> 3);
  const int st_col = ((lane & 7) ^ (lane >> 3)) * 8;
  const int lds_o  = w * 1024 + lane * 16;  // bytes

  f32x4 acc[4][4] = {};
  const int wm = (w >> 1) * 64, wn = (w & 1) * 64;

  for (int k0 = 0; k0 < K; k0 += 64) {
#pragma unroll
    for (int c = 0; c < 4; ++c) {
      gld_lds16(Ap + (size_t)(c * 32 + st_row) * lda + k0 + st_col,
                (char*)Asm + c * 4096 + lds_o);
      gld_lds16(Bp + (size_t)(c * 32 + st_row) * ldb + k0 + st_col,
                (char*)Bsm + c * 4096 + lds_o);
    }
    __syncthreads();
#pragma unroll
    for (int ks = 0; ks < 2; ++ks) {
      s16x8 af[4], bfr[4];
#pragma unroll
      for (int i = 0; i < 4; ++i) {
        const int r  = wm + i * 16 + (lane & 15);
        const int cl = ks * 4 + (lane >> 4);
        af[i] = *(const s16x8*)((const char*)Asm + r * 128 + ((cl ^ (r & 7)) * 16));
      }
#pragma unroll
      for (int j = 0; j < 4; ++j) {
        const int r  = wn + j * 16 + (lane & 15);
        const int cl = ks * 4 + (lane >> 4);
        bfr[j] = *(const s16x8*)((const char*)Bsm + r * 128 + ((cl ^ (r & 7)) * 16));
      }
#pragma unroll
      for (int i = 0; i < 4; ++i)
#pragma unroll
        for (int j = 0; j < 4; ++j)
          acc[i][j] = __builtin_amdgcn_mfma_f32_16x16x32_bf16(af[i], bfr[j], acc[i][j], 0, 0, 0);
    }
    __syncthreads();
  }

  // epilogue: C/D layout col=lane&15, row=(lane>>4)*4+reg  (m89/m91 verified mapping)
  const int r0b = bm * 128 + wm + (lane >> 4) * 4;
  const int c0b = bn * 128 + wn + (lane & 15);
#pragma unroll
  for (int i = 0; i < 4; ++i) {
#pragma unroll
    for (int j = 0; j < 4; ++j) {
      const int c0 = c0b + j * 16;
#pragma unroll
      for (int r = 0; r < 4; ++r) {
        const int rr = r0b + i * 16 + r;
        const size_t idx = (size_t)rr * ldc + c0;
        const float val = acc[i][j][r];
        if constexpr (EPI == 0) {
          ((unsigned short*)Cv)[idx] = f2b(val + bias[c0]);
        } else if constexpr (EPI == 1) {
          ((unsigned short*)Cv)[idx] = f2b(val);
        } else if constexpr (EPI == 2) {
          ((unsigned short*)Cv)[idx] = f2b(val * 0.03125f);  // 1/sqrt(1024)
        } else {
          ((float*)Cv)[idx] = val * norms[rr] * rs[rr];
        }
      }
    }
  }
}

// ---------------- row softmax, in place, keeps P unnormalized + stores 1/sum ----------------
__global__ void softmax_rows(unsigned short* __restrict__ S, float* __restrict__ rs) {
  const int row = blockIdx.x;
  const int tid = threadIdx.x, lane = tid & 63, w = tid >> 6;
  unsigned short* sr = S + (size_t)row * SS;
  u16x8 raw = *(const u16x8*)(sr + tid * 8);
  float v[8]; float m = -1e30f;
#pragma unroll
  for (int j = 0; j < 8; ++j) { v[j] = b2f(raw[j]); m = fmaxf(m, v[j]); }
#pragma unroll
  for (int o = 32; o; o >>= 1) m = fmaxf(m, __shfl_xor(m, o));
  __shared__ float mx[4], sm[4];
  if (lane == 0) mx[w] = m;
  __syncthreads();
  m = fmaxf(fmaxf(mx[0], mx[1]), fmaxf(mx[2], mx[3]));
  float s = 0.f;
#pragma unroll
  for (int j = 0; j < 8; ++j) { v[j] = __expf(v[j] - m); s += v[j]; }
#pragma unroll
  for (int o = 32; o; o >>= 1) s += __shfl_xor(s, o);
  if (lane == 0) sm[w] = s;
  __syncthreads();
  s = sm[0] + sm[1] + sm[2] + sm[3];
  u16x8 ow;
#pragma unroll
  for (int j = 0; j < 8; ++j) ow[j] = f2b(v[j]);
  *(u16x8*)(sr + tid * 8) = ow;
  if (tid == 0) rs[row] = 1.0f / s;
}

extern "C" void kernel_launch(void* const* d_in, const int* in_sizes, int n_in,
                              void* d_out, int out_size, void* d_ws, size_t ws_size,
                              hipStream_t stream) {
  (void)in_sizes; (void)n_in; (void)out_size; (void)ws_size;
  const float* X  = (const float*)d_in[0];
  const float* Wq = (const float*)d_in[1];
  const float* bq = (const float*)d_in[2];
  const float* Wv = (const float*)d_in[3];
  const float* bv = (const float*)d_in[4];
  const float* Am = (const float*)d_in[5];

  char* ws = (char*)d_ws;
  size_t off = 0;
  auto alloc = [&](size_t bytes) { char* p = ws + off; off += (bytes + 255) & ~255ull; return p; };
  float* norms          = (float*)alloc((size_t)MROWS * 4);
  float* rs             = (float*)alloc((size_t)MROWS * 4);
  unsigned short* Wqb   = (unsigned short*)alloc((size_t)H * H * 2);
  unsigned short* Wvb   = (unsigned short*)alloc((size_t)H * H * 2);
  unsigned short* Atb   = (unsigned short*)alloc((size_t)H * H * 2);
  unsigned short* Qb    = (unsigned short*)alloc((size_t)MROWS * H * 2);
  unsigned short* TQb   = (unsigned short*)alloc((size_t)MROWS * H * 2);
  unsigned short* VTb   = (unsigned short*)alloc((size_t)MROWS * H * 2);
  unsigned short* Xs    = (unsigned short*)alloc((size_t)MROWS * H * 2);  // dead after v GEMM
  unsigned short* Vb    = (unsigned short*)alloc((size_t)MROWS * H * 2);  // dead after transpose
  unsigned short* Sc    = Xs;  // scores [16384][2048] bf16 aliases Xs+Vb (64 MB), live later

  // 1) norms + scaled cast
  norms_cast<<<MROWS / 4, 256, 0, stream>>>(X, Xs, norms);
  // 2) weight casts + A^T
  cast_f32_bf16<<<H * H / 1024, 256, 0, stream>>>(Wq, Wqb);
  cast_f32_bf16<<<H * H / 1024, 256, 0, stream>>>(Wv, Wvb);
  transpose_cast_f32<<<dim3(H / 32, H / 32), dim3(32, 8), 0, stream>>>(Am, Atb);
  // 3) q = Xs @ Wq^T + bq ; v = Xs @ Wv^T + bv
  gemm_nt<0><<<dim3(H / 128, MROWS / 128), 256, 0, stream>>>(Xs, H, Wqb, H, 0, Qb, H, bq, nullptr, nullptr, H);
  gemm_nt<0><<<dim3(H / 128, MROWS / 128), 256, 0, stream>>>(Xs, H, Wvb, H, 0, Vb, H, bv, nullptr, nullptr, H);
  // 4) vT per batch
  transpose_bf16<<<dim3(H / 32, SS / 32, BB), dim3(32, 8), 0, stream>>>(Vb, VTb);
  // 5) tq = q @ A  (via A^T, NT)
  gemm_nt<1><<<dim3(H / 128, MROWS / 128), 256, 0, stream>>>(Qb, H, Atb, H, 0, TQb, H, nullptr, nullptr, nullptr, H);
  // 6) scores = q @ tq^T / 32   (batched over b via strideB)
  gemm_nt<2><<<dim3(SS / 128, MROWS / 128), 256, 0, stream>>>(Qb, H, TQb, H, (long)SS * H, Sc, SS, nullptr, nullptr, nullptr, H);
  // 7) softmax rows (in place, unnormalized) + 1/sum
  softmax_rows<<<MROWS, 256, 0, stream>>>(Sc, rs);
  // 8) out = (P @ vT^T) * norm[row] * (1/sum[row])
  gemm_nt<3><<<dim3(H / 128, MROWS / 128), 256, 0, stream>>>(Sc, SS, VTb, SS, (long)H * SS, d_out, H, nullptr, norms, rs, SS);
}

// Round 4
// 407.979 us; speedup vs baseline: 1.1321x; 1.1321x over previous
//
#include <hip/hip_runtime.h>
#include <cstdint>
#include <cstddef>

#define H 1024
#define BB 8
#define SS 2048
#define MROWS (BB*SS)   // 16384

typedef float  f32x4 __attribute__((ext_vector_type(4)));
typedef short  s16x8 __attribute__((ext_vector_type(8)));
typedef unsigned short u16x4 __attribute__((ext_vector_type(4)));
typedef unsigned short u16x8 __attribute__((ext_vector_type(8)));

__device__ __forceinline__ float b2f(unsigned short u) {
  union { unsigned int i; float f; } x; x.i = ((unsigned int)u) << 16; return x.f;
}
__device__ __forceinline__ unsigned short f2b(float f) {
  union { float f; unsigned int i; } x; x.f = f;
  unsigned int r = x.i + 0x7FFFu + ((x.i >> 16) & 1u);
  return (unsigned short)(r >> 16);
}

typedef __attribute__((address_space(1))) unsigned int guint;
typedef __attribute__((address_space(3))) unsigned int luint;
__device__ __forceinline__ void gld_lds16(const void* g, void* l) {
  __builtin_amdgcn_global_load_lds((guint*)g, (luint*)l, 16, 0, 0);
}

// ---------------- norms + scale + cast to bf16 ----------------
__global__ void norms_cast(const float* __restrict__ X, unsigned short* __restrict__ Xs,
                           float* __restrict__ norms) {
  const int row  = blockIdx.x * 4 + (threadIdx.x >> 6);
  const int lane = threadIdx.x & 63;
  const float4* xr = (const float4*)(X + (size_t)row * H);
  float4 d[4]; float s = 0.f;
#pragma unroll
  for (int j = 0; j < 4; ++j) {
    d[j] = xr[lane + j * 64];
    s += d[j].x*d[j].x + d[j].y*d[j].y + d[j].z*d[j].z + d[j].w*d[j].w;
  }
#pragma unroll
  for (int o = 32; o; o >>= 1) s += __shfl_xor(s, o);
  const float nrm = sqrtf(s);
  const float inv = 1.f / (nrm + 1e-9f);
  if (lane == 0) norms[row] = nrm;
  unsigned short* xo = Xs + (size_t)row * H;
#pragma unroll
  for (int j = 0; j < 4; ++j) {
    u16x4 o4;
    o4[0] = f2b(d[j].x * inv); o4[1] = f2b(d[j].y * inv);
    o4[2] = f2b(d[j].z * inv); o4[3] = f2b(d[j].w * inv);
    *(u16x4*)(xo + (size_t)(lane + j * 64) * 4) = o4;
  }
}

// ---------------- elementwise cast ----------------
__global__ void cast_f32_bf16(const float* __restrict__ in, unsigned short* __restrict__ out) {
  const size_t i = ((size_t)blockIdx.x * 256 + threadIdx.x) * 4;
  float4 d = *(const float4*)(in + i);
  u16x4 o; o[0] = f2b(d.x); o[1] = f2b(d.y); o[2] = f2b(d.z); o[3] = f2b(d.w);
  *(u16x4*)(out + i) = o;
}

// ---------------- transpose fp32 -> bf16 (anomaly matrix) ----------------
__global__ void transpose_cast_f32(const float* __restrict__ in, unsigned short* __restrict__ out) {
  __shared__ float t[32][33];
  const int c0 = blockIdx.x * 32, r0 = blockIdx.y * 32;
  const int tx = threadIdx.x, ty = threadIdx.y;
#pragma unroll
  for (int j = 0; j < 4; ++j)
    t[ty + j * 8][tx] = in[(size_t)(r0 + ty + j * 8) * H + c0 + tx];
  __syncthreads();
#pragma unroll
  for (int j = 0; j < 4; ++j)
    out[(size_t)(c0 + ty + j * 8) * H + r0 + tx] = f2b(t[tx][ty + j * 8]);
}

// ---------------- batched bf16 transpose (v -> vT per batch) ----------------
__global__ void transpose_bf16(const unsigned short* __restrict__ in, unsigned short* __restrict__ out) {
  __shared__ unsigned short t[32][33];
  const size_t zo = (size_t)blockIdx.z * SS * H;
  const int c0 = blockIdx.x * 32, r0 = blockIdx.y * 32;
  const int tx = threadIdx.x, ty = threadIdx.y;
#pragma unroll
  for (int j = 0; j < 4; ++j)
    t[ty + j * 8][tx] = in[zo + (size_t)(r0 + ty + j * 8) * H + c0 + tx];
  __syncthreads();
#pragma unroll
  for (int j = 0; j < 4; ++j)
    out[zo + (size_t)(c0 + ty + j * 8) * SS + r0 + tx] = t[tx][ty + j * 8];
}

// ---------------- NT GEMM, 256x256 tile, BK=32, 4-deep LDS ring, counted vmcnt ----------------
// C[m,n] = sum_k A[m,k]*B[n,k]. 512 threads = 8 waves (2M x 4N), per-wave 128x64 output.
// Pipeline per K-tile t: STAGE(t+2) -> vmcnt(8) (t landed; t+1,t+2 in flight) -> s_barrier
//   -> 12x ds_read_b128 + 32x MFMA. ONE barrier per K-tile; never drains vmcnt to 0 in loop.
// Race proof: buf x staged at iter t was last read at iter t-2; those reads are lgkm-drained
// before that wave reaches barrier(t-1), and the stage is issued only after barrier(t-1).
// LDS swizzle: slot ^= (row>>1)&3 (2 lanes/bank = free); source pre-swizzled (rule 21),
// gld_lds dest linear (= tid order, wave base + lane*16).
// EPI: 0 = bf16 + bias[col]; 1 = bf16; 2 = bf16 * 1/32; 3 = f32 * norms[row]*rs[row]
template <int EPI, int TK>   // TK = K/32, must be >= 3
__global__ __launch_bounds__(512, 2)
void gemm_nt(const unsigned short* __restrict__ A, int lda,
             const unsigned short* __restrict__ B0, int ldb, long sB,
             void* __restrict__ Cv, int ldc,
             const float* __restrict__ bias,
             const float* __restrict__ norms, const float* __restrict__ rs) {
  __shared__ __align__(16) unsigned short lds[4][2][256 * 32];  // 128 KiB
  const int tid = threadIdx.x, lane = tid & 63, w = tid >> 6;

  // bijective XCD swizzle (all grids have nwg % 8 == 0)
  const int nx = gridDim.x;
  int bid = blockIdx.y * nx + blockIdx.x;
  bid = (bid & 7) * ((nx * (int)gridDim.y) >> 3) + (bid >> 3);
  const int bn = bid % nx, bm = bid / nx;

  const unsigned short* Ap = A  + (size_t)bm * 256 * lda;
  const unsigned short* Bp = B0 + (size_t)(bm >> 3) * sB + (size_t)bn * 256 * ldb;

  // staging: thread -> (row = tid>>2 within 128-row half, slot = tid&3); source slot
  // pre-swizzled so LDS[r][s] = G[r][s ^ ((r>>1)&3)] with a linear LDS destination.
  const int sr    = tid >> 2;
  const int gslot = (tid & 3) ^ ((sr >> 1) & 3);
  const unsigned short* As0 = Ap + (size_t)sr * lda + gslot * 8;
  const unsigned short* Bs0 = Bp + (size_t)sr * ldb + gslot * 8;

  auto STAGE = [&](int kt, int q) {
    const unsigned short* as = As0 + kt * 32;
    const unsigned short* bs = Bs0 + kt * 32;
    unsigned short* la = &lds[q][0][0] + tid * 8;
    unsigned short* lb = &lds[q][1][0] + tid * 8;
    gld_lds16(as,                       la);
    gld_lds16(as + (size_t)128 * lda,   la + 4096);
    gld_lds16(bs,                       lb);
    gld_lds16(bs + (size_t)128 * ldb,   lb + 4096);
  };

  const int wm = w >> 2, wn = w & 3;       // 2 x 4 wave grid
  const int rA = lane & 15;
  const int ssw = ((lane >> 4) ^ ((rA >> 1) & 3)) * 8;  // swizzled k-slot (ushort offset)
  f32x4 acc[8][4] = {};

  auto COMPUTE = [&](int t) {
    const unsigned short* pa = &lds[t & 3][0][0] + (size_t)(wm * 128 + rA) * 32 + ssw;
    const unsigned short* pb = &lds[t & 3][1][0] + (size_t)(wn * 64  + rA) * 32 + ssw;
    s16x8 af[8], bf[4];
#pragma unroll
    for (int i = 0; i < 8; ++i) af[i] = *(const s16x8*)(pa + i * 512);
#pragma unroll
    for (int j = 0; j < 4; ++j) bf[j] = *(const s16x8*)(pb + j * 512);
    __builtin_amdgcn_s_setprio(1);
#pragma unroll
    for (int i = 0; i < 8; ++i)
#pragma unroll
      for (int j = 0; j < 4; ++j)
        acc[i][j] = __builtin_amdgcn_mfma_f32_16x16x32_bf16(af[i], bf[j], acc[i][j], 0, 0, 0);
    __builtin_amdgcn_s_setprio(0);
  };

  STAGE(0, 0);
  STAGE(1, 1);
#pragma unroll 1
  for (int t = 0; t < TK - 2; ++t) {
    STAGE(t + 2, (t + 2) & 3);
    asm volatile("s_waitcnt vmcnt(8)" ::: "memory");
    __builtin_amdgcn_s_barrier();
    COMPUTE(t);
  }
  asm volatile("s_waitcnt vmcnt(4)" ::: "memory");
  __builtin_amdgcn_s_barrier();
  COMPUTE(TK - 2);
  asm volatile("s_waitcnt vmcnt(0)" ::: "memory");
  __builtin_amdgcn_s_barrier();
  COMPUTE(TK - 1);

  // epilogue: C/D layout col = lane&15, row = (lane>>4)*4 + reg (m89/m91)
  const int r0b = bm * 256 + wm * 128 + (lane >> 4) * 4;
  const int c0b = bn * 256 + wn * 64 + rA;
#pragma unroll
  for (int i = 0; i < 8; ++i) {
#pragma unroll
    for (int j = 0; j < 4; ++j) {
      const int cc = c0b + j * 16;
#pragma unroll
      for (int r = 0; r < 4; ++r) {
        const int rr = r0b + i * 16 + r;
        const size_t idx = (size_t)rr * ldc + cc;
        const float val = acc[i][j][r];
        if constexpr (EPI == 0) {
          ((unsigned short*)Cv)[idx] = f2b(val + bias[cc]);
        } else if constexpr (EPI == 1) {
          ((unsigned short*)Cv)[idx] = f2b(val);
        } else if constexpr (EPI == 2) {
          ((unsigned short*)Cv)[idx] = f2b(val * 0.03125f);  // 1/sqrt(1024)
        } else {
          ((float*)Cv)[idx] = val * norms[rr] * rs[rr];
        }
      }
    }
  }
}

// ---------------- row softmax, in place, keeps P unnormalized + stores 1/sum ----------------
__global__ void softmax_rows(unsigned short* __restrict__ S, float* __restrict__ rs) {
  const int row = blockIdx.x;
  const int tid = threadIdx.x, lane = tid & 63, w = tid >> 6;
  unsigned short* sr = S + (size_t)row * SS;
  u16x8 raw = *(const u16x8*)(sr + tid * 8);
  float v[8]; float m = -1e30f;
#pragma unroll
  for (int j = 0; j < 8; ++j) { v[j] = b2f(raw[j]); m = fmaxf(m, v[j]); }
#pragma unroll
  for (int o = 32; o; o >>= 1) m = fmaxf(m, __shfl_xor(m, o));
  __shared__ float mx[4], sm[4];
  if (lane == 0) mx[w] = m;
  __syncthreads();
  m = fmaxf(fmaxf(mx[0], mx[1]), fmaxf(mx[2], mx[3]));
  float s = 0.f;
#pragma unroll
  for (int j = 0; j < 8; ++j) { v[j] = __expf(v[j] - m); s += v[j]; }
#pragma unroll
  for (int o = 32; o; o >>= 1) s += __shfl_xor(s, o);
  if (lane == 0) sm[w] = s;
  __syncthreads();
  s = sm[0] + sm[1] + sm[2] + sm[3];
  u16x8 ow;
#pragma unroll
  for (int j = 0; j < 8; ++j) ow[j] = f2b(v[j]);
  *(u16x8*)(sr + tid * 8) = ow;
  if (tid == 0) rs[row] = 1.0f / s;
}

extern "C" void kernel_launch(void* const* d_in, const int* in_sizes, int n_in,
                              void* d_out, int out_size, void* d_ws, size_t ws_size,
                              hipStream_t stream) {
  (void)in_sizes; (void)n_in; (void)out_size; (void)ws_size;
  const float* X  = (const float*)d_in[0];
  const float* Wq = (const float*)d_in[1];
  const float* bq = (const float*)d_in[2];
  const float* Wv = (const float*)d_in[3];
  const float* bv = (const float*)d_in[4];
  const float* Am = (const float*)d_in[5];

  char* ws = (char*)d_ws;
  size_t off = 0;
  auto alloc = [&](size_t bytes) { char* p = ws + off; off += (bytes + 255) & ~255ull; return p; };
  float* norms          = (float*)alloc((size_t)MROWS * 4);
  float* rs             = (float*)alloc((size_t)MROWS * 4);
  unsigned short* Wqb   = (unsigned short*)alloc((size_t)H * H * 2);
  unsigned short* Wvb   = (unsigned short*)alloc((size_t)H * H * 2);
  unsigned short* Atb   = (unsigned short*)alloc((size_t)H * H * 2);
  unsigned short* Qb    = (unsigned short*)alloc((size_t)MROWS * H * 2);
  unsigned short* TQb   = (unsigned short*)alloc((size_t)MROWS * H * 2);
  unsigned short* VTb   = (unsigned short*)alloc((size_t)MROWS * H * 2);
  unsigned short* Xs    = (unsigned short*)alloc((size_t)MROWS * H * 2);  // dead after v GEMM
  unsigned short* Vb    = (unsigned short*)alloc((size_t)MROWS * H * 2);  // dead after transpose
  unsigned short* Sc    = Xs;  // scores [16384][2048] bf16 aliases Xs+Vb (64 MB), live later

  // 1) norms + scaled cast
  norms_cast<<<MROWS / 4, 256, 0, stream>>>(X, Xs, norms);
  // 2) weight casts + A^T
  cast_f32_bf16<<<H * H / 1024, 256, 0, stream>>>(Wq, Wqb);
  cast_f32_bf16<<<H * H / 1024, 256, 0, stream>>>(Wv, Wvb);
  transpose_cast_f32<<<dim3(H / 32, H / 32), dim3(32, 8), 0, stream>>>(Am, Atb);
  // 3) q = Xs @ Wq^T + bq ; v = Xs @ Wv^T + bv   (grid 4x64 = 256 blocks)
  gemm_nt<0, 32><<<dim3(H / 256, MROWS / 256), 512, 0, stream>>>(Xs, H, Wqb, H, 0, Qb, H, bq, nullptr, nullptr);
  gemm_nt<0, 32><<<dim3(H / 256, MROWS / 256), 512, 0, stream>>>(Xs, H, Wvb, H, 0, Vb, H, bv, nullptr, nullptr);
  // 4) vT per batch
  transpose_bf16<<<dim3(H / 32, SS / 32, BB), dim3(32, 8), 0, stream>>>(Vb, VTb);
  // 5) tq = q @ A  (via A^T, NT)
  gemm_nt<1, 32><<<dim3(H / 256, MROWS / 256), 512, 0, stream>>>(Qb, H, Atb, H, 0, TQb, H, nullptr, nullptr, nullptr);
  // 6) scores = q @ tq^T / 32   (batched over b via strideB; grid 8x64 = 512 blocks)
  gemm_nt<2, 32><<<dim3(SS / 256, MROWS / 256), 512, 0, stream>>>(Qb, H, TQb, H, (long)SS * H, Sc, SS, nullptr, nullptr, nullptr);
  // 7) softmax rows (in place, unnormalized) + 1/sum
  softmax_rows<<<MROWS, 256, 0, stream>>>(Sc, rs);
  // 8) out = (P @ vT^T) * norm[row] * (1/sum[row])   (K = 2048 -> TK = 64)
  gemm_nt<3, 64><<<dim3(H / 256, MROWS / 256), 512, 0, stream>>>(Sc, SS, VTb, SS, (long)H * SS, d_out, H, nullptr, norms, rs);
}